// Round 15
// baseline (222.722 us; speedup 1.0000x reference)
//
#include <hip/hip_runtime.h>
#include <math.h>

typedef __attribute__((ext_vector_type(8))) short bf16x8;
typedef __attribute__((ext_vector_type(4))) float f32x4;

__device__ __forceinline__ unsigned short f2b(float f) {
    union { float f; unsigned int u; } v; v.f = f;
    unsigned int u = v.u + 0x7FFFu + ((v.u >> 16) & 1u);  // RNE
    return (unsigned short)(u >> 16);
}

__device__ __forceinline__ f32x4 mfma16(bf16x8 a, bf16x8 b, f32x4 c) {
    return __builtin_amdgcn_mfma_f32_16x16x32_bf16(a, b, c, 0, 0, 0);
}

__device__ __forceinline__ void async_ld16(void* l, const void* g) {
    __builtin_amdgcn_global_load_lds(
        (__attribute__((address_space(1))) void*)g,
        (__attribute__((address_space(3))) void*)l, 16, 0, 0);
}

// hardware exp2 (scores are pre-scaled by log2e in the Q projection)
__device__ __forceinline__ float exp2_hw(float x) {
    float r; asm("v_exp_f32 %0, %1" : "=v"(r) : "v"(x)); return r;
}

// pack two fp32 -> two bf16 (lo = a, hi = b) in one instruction (RNE)
__device__ __forceinline__ unsigned int cvtpk_bf16(float a, float b) {
    unsigned int r;
    asm("v_cvt_pk_bf16_f32 %0, %1, %2" : "=v"(r) : "v"(a), "v"(b));
    return r;
}

// ---------------------------------------------------------------------------
// MERGED prep kernel:
//   blocks [0, 12288): fp32->bf16 convert of q/k/v (3 x 4096 blocks)
//   blocks [12288, 13312): convert+transpose of Wq/Wk/Wv/Wo (4 x 256 blocks)
// ---------------------------------------------------------------------------
__global__ __launch_bounds__(256) void prep(
    const float* __restrict__ q, const float* __restrict__ k,
    const float* __restrict__ v, unsigned short* __restrict__ qo,
    unsigned short* __restrict__ ko, unsigned short* __restrict__ vo,
    const float* __restrict__ W0, const float* __restrict__ W1,
    const float* __restrict__ W2, const float* __restrict__ W3,
    unsigned short* __restrict__ T0, unsigned short* __restrict__ T1,
    unsigned short* __restrict__ T2, unsigned short* __restrict__ T3)
{
    __shared__ short Ls[64 * 65];
    const int bid = blockIdx.x;
    const int t = threadIdx.x;
    if (bid < 12288) {
        const int z = bid >> 12, blk = bid & 4095;
        const float* in = (z == 0) ? q : (z == 1) ? k : v;
        unsigned short* out = (z == 0) ? qo : (z == 1) ? ko : vo;
        const int i = (blk * 256 + t) * 4;
        const float4 x = *(const float4*)(in + i);
        ushort4 o; o.x = f2b(x.x); o.y = f2b(x.y); o.z = f2b(x.z); o.w = f2b(x.w);
        *(ushort4*)(out + i) = o;
        return;
    }
    const int r = bid - 12288;                   // [0,1024)
    const int z = r >> 8, rem = r & 255;
    const int k0 = (rem >> 4) * 64, n0 = (rem & 15) * 64;
    const float* W = (z == 0) ? W0 : (z == 1) ? W1 : (z == 2) ? W2 : W3;
    unsigned short* T = (z == 0) ? T0 : (z == 1) ? T1 : (z == 2) ? T2 : T3;
#pragma unroll
    for (int ii = 0; ii < 4; ++ii) {
        const int kl = (t >> 4) + 16 * ii, nl = (t & 15) * 4;
        const float4 vv = *(const float4*)&W[(size_t)(k0 + kl) * 1024 + n0 + nl];
        Ls[kl * 65 + nl + 0] = (short)f2b(vv.x);
        Ls[kl * 65 + nl + 1] = (short)f2b(vv.y);
        Ls[kl * 65 + nl + 2] = (short)f2b(vv.z);
        Ls[kl * 65 + nl + 3] = (short)f2b(vv.w);
    }
    __syncthreads();
#pragma unroll
    for (int ii = 0; ii < 4; ++ii) {
        const int nl = (t >> 4) + 16 * ii, kl = (t & 15) * 4;
        ushort4 o;
        o.x = (unsigned short)Ls[(kl + 0) * 65 + nl];
        o.y = (unsigned short)Ls[(kl + 1) * 65 + nl];
        o.z = (unsigned short)Ls[(kl + 2) * 65 + nl];
        o.w = (unsigned short)Ls[(kl + 3) * 65 + nl];
        *(ushort4*)&T[(size_t)(n0 + nl) * 1024 + k0 + kl] = o;
    }
}

// ---------------------------------------------------------------------------
// MERGED projection GEMM: [4096x1024]bf16 x Bt[3072x1024]^T. BK=64 with
// XOR-swizzled LDS (source col-block (t&7)^((t>>3)&7), linear dest, XOR'd
// read). XCD-panel-chunked: 24 n-tiles per m-panel all on one XCD.
// ---------------------------------------------------------------------------
__global__ __launch_bounds__(256) void gemm_proj(
    const unsigned short* __restrict__ qb, const unsigned short* __restrict__ kb,
    const unsigned short* __restrict__ vb,
    const unsigned short* __restrict__ BtAll,   // merged [3072][1024]
    unsigned short* __restrict__ Qw, unsigned short* __restrict__ Kw,
    unsigned short* __restrict__ Vw,
    const float* __restrict__ iq, const float* __restrict__ ik,
    const float* __restrict__ iv)
{
    const unsigned hw = blockIdx.x;
    const unsigned xcd = hw & 7, j = hw >> 3;       // j in [0,96)
    const unsigned mloc = j / 24, ntg = j - mloc * 24;
    const int mt = (int)(xcd * 4 + mloc);
    const int z = (int)(ntg >> 3), ntl = (int)(ntg & 7);
    const int m0 = mt * 128, n0 = (int)ntg * 128;

    const unsigned short* A = (z == 0) ? qb : (z == 1) ? kb : vb;
    unsigned short* Cw      = (z == 0) ? Qw : (z == 1) ? Kw : Vw;
    const float* msk        = (z == 0) ? iq : (z == 1) ? ik : iv;
    const float scale = (z == 0) ? 0.125f * 1.44269504088896f : 1.0f;

    __shared__ __align__(16) short As[128 * 64];
    __shared__ __align__(16) short Bs[128 * 64];
    __shared__ float maskL[128];
    const int t = threadIdx.x;
    const int w = t >> 6, lane = t & 63, l15 = lane & 15, quad = lane >> 4;
    const int wr = w >> 1, wc = w & 1;
    if (t < 128) maskL[t] = msk[m0 + t] * scale;

    const int srow = t >> 3;
    const int scol = ((t & 7) ^ ((t >> 3) & 7)) * 8;   // constant per thread
    const int l7 = l15 & 7;

    f32x4 zero4 = {0.f, 0.f, 0.f, 0.f};
    f32x4 acc[4][4];
#pragma unroll
    for (int i = 0; i < 4; ++i)
#pragma unroll
        for (int j2 = 0; j2 < 4; ++j2) acc[i][j2] = zero4;

    for (int k0 = 0; k0 < 1024; k0 += 64) {
        __syncthreads();
#pragma unroll
        for (int u = 0; u < 4; ++u) {
            const int r = u * 32 + srow;
            async_ld16(As + u * 2048 + t * 8, A     + (size_t)(m0 + r) * 1024 + k0 + scol);
            async_ld16(Bs + u * 2048 + t * 8, BtAll + (size_t)(n0 + r) * 1024 + k0 + scol);
        }
        __syncthreads();
#pragma unroll
        for (int ks = 0; ks < 2; ++ks) {
            const int cb = ((4 * ks + quad) ^ l7) * 8;  // swizzled read colblk
            bf16x8 af[4], bfr[4];
#pragma unroll
            for (int i = 0; i < 4; ++i)
                af[i] = *(const bf16x8*)&As[(64 * wr + 16 * i + l15) * 64 + cb];
#pragma unroll
            for (int j2 = 0; j2 < 4; ++j2)
                bfr[j2] = *(const bf16x8*)&Bs[(64 * wc + 16 * j2 + l15) * 64 + cb];
            __builtin_amdgcn_s_setprio(1);
#pragma unroll
            for (int i = 0; i < 4; ++i)
#pragma unroll
                for (int j2 = 0; j2 < 4; ++j2)
                    acc[i][j2] = mfma16(af[i], bfr[j2], acc[i][j2]);
            __builtin_amdgcn_s_setprio(0);
        }
    }

    const int h = 2 * ntl + wc;  // 64-col wave tile == one head
#pragma unroll
    for (int i = 0; i < 4; ++i)
#pragma unroll
        for (int j2 = 0; j2 < 4; ++j2)
#pragma unroll
            for (int reg = 0; reg < 4; ++reg) {
                const int mloc2 = 64 * wr + 16 * i + 4 * quad + reg;
                const int m = m0 + mloc2;
                const int bb = m >> 11, s = m & 2047;
                const int hd = 16 * j2 + l15;
                Cw[((size_t)(bb * 16 + h) * 2048 + s) * 64 + hd] =
                    f2b(acc[i][j2][reg] * maskL[mloc2]);
            }
}

// ---------------------------------------------------------------------------
// Output GEMM: out[4096x1024]f32 = AO bf16 @ Wot^T. BM=128 BN=64, BK=64,
// XOR-swizzle, XCD-panel-chunked grid 512.
// ---------------------------------------------------------------------------
__global__ __launch_bounds__(256) void gemm_out(
    const unsigned short* __restrict__ A, const unsigned short* __restrict__ Bt,
    float* __restrict__ C)
{
    __shared__ __align__(16) short As[128 * 64];
    __shared__ __align__(16) short Bs[64 * 64];
    const int t = threadIdx.x;
    const int w = t >> 6, lane = t & 63, l15 = lane & 15, quad = lane >> 4;
    const int wr = w >> 1, wc = w & 1;
    const unsigned hw = blockIdx.x;
    const unsigned xcd = hw & 7, j = hw >> 3;
    const unsigned mt = xcd * 4 + (j >> 4);
    const unsigned nt = j & 15;
    const int n0 = nt * 64, m0 = mt * 128;

    const int srow = t >> 3;
    const int scol = ((t & 7) ^ ((t >> 3) & 7)) * 8;   // constant per thread
    const int l7 = l15 & 7;

    f32x4 zero4 = {0.f, 0.f, 0.f, 0.f};
    f32x4 acc[4][2];
#pragma unroll
    for (int i = 0; i < 4; ++i) { acc[i][0] = zero4; acc[i][1] = zero4; }

    for (int k0 = 0; k0 < 1024; k0 += 64) {
        __syncthreads();
#pragma unroll
        for (int u = 0; u < 4; ++u)
            async_ld16(As + u * 2048 + t * 8, A + (size_t)(m0 + u * 32 + srow) * 1024 + k0 + scol);
#pragma unroll
        for (int u = 0; u < 2; ++u)
            async_ld16(Bs + u * 2048 + t * 8, Bt + (size_t)(n0 + u * 32 + srow) * 1024 + k0 + scol);
        __syncthreads();
#pragma unroll
        for (int ks = 0; ks < 2; ++ks) {
            const int cb = ((4 * ks + quad) ^ l7) * 8;
            bf16x8 af[4], bfr[2];
#pragma unroll
            for (int i = 0; i < 4; ++i)
                af[i] = *(const bf16x8*)&As[(64 * wr + 16 * i + l15) * 64 + cb];
#pragma unroll
            for (int jj = 0; jj < 2; ++jj)
                bfr[jj] = *(const bf16x8*)&Bs[(32 * wc + 16 * jj + l15) * 64 + cb];
            __builtin_amdgcn_s_setprio(1);
#pragma unroll
            for (int i = 0; i < 4; ++i)
#pragma unroll
                for (int jj = 0; jj < 2; ++jj)
                    acc[i][jj] = mfma16(af[i], bfr[jj], acc[i][jj]);
            __builtin_amdgcn_s_setprio(0);
        }
    }
#pragma unroll
    for (int i = 0; i < 4; ++i)
#pragma unroll
        for (int jj = 0; jj < 2; ++jj)
#pragma unroll
            for (int reg = 0; reg < 4; ++reg) {
                const int m = m0 + 64 * wr + 16 * i + 4 * quad + reg;
                const int n = n0 + 32 * wc + 16 * jj + l15;
                C[(size_t)m * 1024 + n] = acc[i][jj][reg];
            }
}

#define GST 72   // attn K LDS row stride (shorts): 144B, b128-aligned
#define VST 136  // attn V LDS row stride (shorts): 272B, b128-aligned; 68 dw = 4 mod 32 (same class as 36)

// ---------------------------------------------------------------------------
// MFMA flash attention v7: round-11 v5 structure with 128-KEY chunks —
// 16 barriers instead of 32 (the diagnosed cost is the per-barrier convoy
// drain; per-key staging/MFMA/exp2 work is unchanged).
//  - Ks[2][128x72] row-swizzled reg-staged K (2 rows/thread).
//  - Vt[2][64xVST] V[dim][key], 128 key cols (2 key-pairs/thread).
//  - LDS 79.9 KB -> still 2 blocks/CU (159.7 <= 160 KB).
//  - Same no-max exp2 softmax, bias table, key-permuted P-in-regs,
//    l via ones-B MFMA, XCD-chunked grid 512.
// ---------------------------------------------------------------------------
__global__ __launch_bounds__(512, 4) void attn_mfma(
    const unsigned short* __restrict__ Qw, const unsigned short* __restrict__ Kw,
    const unsigned short* __restrict__ Vw, const float* __restrict__ indk,
    unsigned short* __restrict__ AO)
{
    __shared__ __align__(16) short Ks[2][128 * GST];
    __shared__ __align__(16) short Vt[2][64 * VST];   // Vt[dim][key 0..127]
    __shared__ float Bl[2048];                         // bias per key, whole seq
    const int t = threadIdx.x;
    const int w = t >> 6, lane = t & 63, l15 = lane & 15, quad = lane >> 4;
    const unsigned wg = (blockIdx.x & 7) * 64 + (blockIdx.x >> 3);
    const int q0 = (wg & 15) * 128;
    const int h = (wg >> 4) & 15, b = wg >> 8;
    const size_t base = (size_t)(b * 16 + h) * (2048 * 64);
    const unsigned short* Qb = Qw + base + (size_t)q0 * 64;
    const unsigned short* Kb = Kw + base;
    const unsigned short* Vb = Vw + base;

    bf16x8 qf[2];
    qf[0] = *(const bf16x8*)&Qb[(16 * w + l15) * 64 + 8 * quad];
    qf[1] = *(const bf16x8*)&Qb[(16 * w + l15) * 64 + 32 + 8 * quad];

    {
        const float4 bi = *(const float4*)&indk[b * 2048 + t * 4];
        float4 bo;
        bo.x = (bi.x - 1.f) * 1e30f; bo.y = (bi.y - 1.f) * 1e30f;
        bo.z = (bi.z - 1.f) * 1e30f; bo.w = (bi.w - 1.f) * 1e30f;
        *(float4*)&Bl[t * 4] = bo;
    }

    // staging assignments (each thread: 2 K rows, 2 V key-pairs)
    const int skr = t >> 3, skc = (t & 7) * 8;
    const int slr = skr ^ (((skr >> 3) & 1) << 2);   // row-swizzle (rows 0..63)
    const int dq = t >> 5, kp2 = (t & 31) * 2;

    bf16x8 kreg[2];
    ushort4 vreg[4];
    kreg[0] = *(const bf16x8*)&Kb[(size_t)skr * 64 + skc];
    kreg[1] = *(const bf16x8*)&Kb[(size_t)(64 + skr) * 64 + skc];
    vreg[0] = *(const ushort4*)&Vb[(size_t)kp2 * 64 + 4 * dq];
    vreg[1] = *(const ushort4*)&Vb[(size_t)(kp2 + 1) * 64 + 4 * dq];
    vreg[2] = *(const ushort4*)&Vb[(size_t)(64 + kp2) * 64 + 4 * dq];
    vreg[3] = *(const ushort4*)&Vb[(size_t)(65 + kp2) * 64 + 4 * dq];

    const int u_ = l15 >> 2, a_ = l15 & 3;
    const int krA = 8 * u_ + 4 * (u_ & 1) + a_;
    const int krB = 8 * u_ + 4 * (1 - (u_ & 1)) + a_;

    union { unsigned int u[4]; bf16x8 b; } ones;
    ones.u[0] = 0x3F803F80u; ones.u[1] = 0x3F803F80u;
    ones.u[2] = 0x3F803F80u; ones.u[3] = 0x3F803F80u;

    f32x4 zero4 = {0.f, 0.f, 0.f, 0.f};
    f32x4 oacc[4];
    oacc[0] = zero4; oacc[1] = zero4; oacc[2] = zero4; oacc[3] = zero4;
    f32x4 lacc = zero4;

    for (int c = 0; c < 16; ++c) {   // 128-key chunks -> 16 barriers
        const int cur = c & 1;
        // 1. write staged regs (chunk c) -> LDS buf cur
        *(bf16x8*)&Ks[cur][slr * GST + skc]        = kreg[0];
        *(bf16x8*)&Ks[cur][(64 + slr) * GST + skc] = kreg[1];
        {
            const unsigned int* v0d = (const unsigned int*)&vreg[0];
            const unsigned int* v1d = (const unsigned int*)&vreg[1];
            const unsigned int* v2d = (const unsigned int*)&vreg[2];
            const unsigned int* v3d = (const unsigned int*)&vreg[3];
            *(unsigned int*)&Vt[cur][(4 * dq + 0) * VST + kp2] =
                __builtin_amdgcn_perm(v1d[0], v0d[0], 0x05040100u);
            *(unsigned int*)&Vt[cur][(4 * dq + 1) * VST + kp2] =
                __builtin_amdgcn_perm(v1d[0], v0d[0], 0x07060302u);
            *(unsigned int*)&Vt[cur][(4 * dq + 2) * VST + kp2] =
                __builtin_amdgcn_perm(v1d[1], v0d[1], 0x05040100u);
            *(unsigned int*)&Vt[cur][(4 * dq + 3) * VST + kp2] =
                __builtin_amdgcn_perm(v1d[1], v0d[1], 0x07060302u);
            *(unsigned int*)&Vt[cur][(4 * dq + 0) * VST + 64 + kp2] =
                __builtin_amdgcn_perm(v3d[0], v2d[0], 0x05040100u);
            *(unsigned int*)&Vt[cur][(4 * dq + 1) * VST + 64 + kp2] =
                __builtin_amdgcn_perm(v3d[0], v2d[0], 0x07060302u);
            *(unsigned int*)&Vt[cur][(4 * dq + 2) * VST + 64 + kp2] =
                __builtin_amdgcn_perm(v3d[1], v2d[1], 0x05040100u);
            *(unsigned int*)&Vt[cur][(4 * dq + 3) * VST + 64 + kp2] =
                __builtin_amdgcn_perm(v3d[1], v2d[1], 0x07060302u);
        }
        __syncthreads();  // the ONLY barrier per chunk
        // 2. issue chunk c+1 loads (clamped; consumed next iter after compute)
        {
            const int kn = (c < 15 ? c + 1 : 15) * 128;
            kreg[0] = *(const bf16x8*)&Kb[(size_t)(kn + skr) * 64 + skc];
            kreg[1] = *(const bf16x8*)&Kb[(size_t)(kn + 64 + skr) * 64 + skc];
            vreg[0] = *(const ushort4*)&Vb[(size_t)(kn + kp2) * 64 + 4 * dq];
            vreg[1] = *(const ushort4*)&Vb[(size_t)(kn + kp2 + 1) * 64 + 4 * dq];
            vreg[2] = *(const ushort4*)&Vb[(size_t)(kn + 64 + kp2) * 64 + 4 * dq];
            vreg[3] = *(const ushort4*)&Vb[(size_t)(kn + 65 + kp2) * 64 + 4 * dq];
        }
        // 3. compute chunk c (128 keys: 8 QK groups, 4 PV key-slots)
        const short* KsC = Ks[cur];
        const short* VtC = Vt[cur];
        const float* BlC = Bl + c * 128;

        f32x4 sacc[8];
#pragma unroll
        for (int g = 0; g < 8; ++g) {
            const float4 bv = *(const float4*)&BlC[32 * (g >> 1) + 4 * (g & 1) + 8 * quad];
            sacc[g][0] = bv.x; sacc[g][1] = bv.y; sacc[g][2] = bv.z; sacc[g][3] = bv.w;
        }
        __builtin_amdgcn_s_setprio(1);
#pragma unroll
        for (int ks = 0; ks < 2; ++ks)
#pragma unroll
            for (int g = 0; g < 8; ++g) {
                const int row = 32 * (g >> 1) + ((g & 1) ? krB : krA);
                const bf16x8 kf = *(const bf16x8*)&KsC[row * GST + 32 * ks + 8 * quad];
                sacc[g] = mfma16(kf, qf[ks], sacc[g]);
            }
        __builtin_amdgcn_s_setprio(0);
        // lane (l15,quad) holds keys 32*(g>>1) + 8*quad + 4*(g&1) + r, query l15

        unsigned int dw[8][2];
#pragma unroll
        for (int g = 0; g < 8; ++g) {
#pragma unroll
            for (int r = 0; r < 4; ++r) sacc[g][r] = exp2_hw(sacc[g][r]);
            dw[g][0] = cvtpk_bf16(sacc[g][0], sacc[g][1]);
            dw[g][1] = cvtpk_bf16(sacc[g][2], sacc[g][3]);
        }

        __builtin_amdgcn_s_setprio(1);
#pragma unroll
        for (int kv = 0; kv < 4; ++kv) {
            union { unsigned int u[4]; bf16x8 b; } pc;
            pc.u[0] = dw[2 * kv][0];     pc.u[1] = dw[2 * kv][1];
            pc.u[2] = dw[2 * kv + 1][0]; pc.u[3] = dw[2 * kv + 1][1];
#pragma unroll
            for (int nj = 0; nj < 4; ++nj) {
                const bf16x8 vbf = *(const bf16x8*)
                    &VtC[(16 * nj + l15) * VST + 32 * kv + 8 * quad];
                oacc[nj] = mfma16(pc.b, vbf, oacc[nj]);
            }
            lacc = mfma16(pc.b, ones.b, lacc);
        }
        __builtin_amdgcn_s_setprio(0);
    }

    float invr[4];
#pragma unroll
    for (int r = 0; r < 4; ++r)
        invr[r] = (lacc[r] > 0.f) ? 1.f / lacc[r] : 0.f;  // zero-row guard
#pragma unroll
    for (int nj = 0; nj < 4; ++nj)
#pragma unroll
        for (int r = 0; r < 4; ++r) {
            const int row = q0 + 16 * w + 4 * quad + r;
            AO[(size_t)(b * 2048 + row) * 1024 + h * 64 + 16 * nj + l15] =
                f2b(oacc[nj][r] * invr[r]);
        }
}

// ---------------------------------------------------------------------------
extern "C" void kernel_launch(void* const* d_in, const int* in_sizes, int n_in,
                              void* d_out, int out_size, void* d_ws, size_t ws_size,
                              hipStream_t stream) {
    const float* q  = (const float*)d_in[0];
    const float* k  = (const float*)d_in[1];
    const float* v  = (const float*)d_in[2];
    const float* iq = (const float*)d_in[3];
    const float* ik = (const float*)d_in[4];
    const float* iv = (const float*)d_in[5];
    const float* Wq = (const float*)d_in[6];
    const float* Wk = (const float*)d_in[7];
    const float* Wv = (const float*)d_in[8];
    const float* Wo = (const float*)d_in[9];
    float* out = (float*)d_out;
    unsigned short* ws = (unsigned short*)d_ws;

    const size_t M1 = 1048576;
    unsigned short* qb  = ws;
    unsigned short* kb  = ws + 4  * M1;
    unsigned short* vb  = ws + 8  * M1;
    unsigned short* Wqt = ws + 12 * M1;  // Wqt|Wkt|Wvt contiguous = merged Bt
    unsigned short* Wkt = ws + 13 * M1;
    unsigned short* Wvt = ws + 14 * M1;
    unsigned short* Wot = ws + 15 * M1;
    unsigned short* Qw  = ws + 16 * M1;
    unsigned short* Kw  = ws + 20 * M1;
    unsigned short* Vw  = ws + 24 * M1;
    unsigned short* AO  = ws + 28 * M1;

    prep<<<dim3(13312, 1, 1), dim3(256), 0, stream>>>(
        q, k, v, qb, kb, vb, Wq, Wk, Wv, Wo, Wqt, Wkt, Wvt, Wot);
    gemm_proj<<<dim3(768, 1, 1), dim3(256), 0, stream>>>(
        qb, kb, vb, Wqt, Qw, Kw, Vw, iq, ik, iv);
    attn_mfma<<<dim3(512, 1, 1), dim3(512), 0, stream>>>(Qw, Kw, Vw, ik, AO);
    gemm_out<<<dim3(512, 1, 1), dim3(256), 0, stream>>>(AO, Wot, out);
}

// Round 16
// 210.319 us; speedup vs baseline: 1.0590x; 1.0590x over previous
//
#include <hip/hip_runtime.h>
#include <math.h>

typedef __attribute__((ext_vector_type(8))) short bf16x8;
typedef __attribute__((ext_vector_type(4))) float f32x4;

__device__ __forceinline__ unsigned short f2b(float f) {
    union { float f; unsigned int u; } v; v.f = f;
    unsigned int u = v.u + 0x7FFFu + ((v.u >> 16) & 1u);  // RNE
    return (unsigned short)(u >> 16);
}

__device__ __forceinline__ f32x4 mfma16(bf16x8 a, bf16x8 b, f32x4 c) {
    return __builtin_amdgcn_mfma_f32_16x16x32_bf16(a, b, c, 0, 0, 0);
}

__device__ __forceinline__ void async_ld16(void* l, const void* g) {
    __builtin_amdgcn_global_load_lds(
        (__attribute__((address_space(1))) void*)g,
        (__attribute__((address_space(3))) void*)l, 16, 0, 0);
}

// hardware exp2 (scores are pre-scaled by log2e in the Q projection)
__device__ __forceinline__ float exp2_hw(float x) {
    float r; asm("v_exp_f32 %0, %1" : "=v"(r) : "v"(x)); return r;
}

// pack two fp32 -> two bf16 (lo = a, hi = b) in one instruction (RNE)
__device__ __forceinline__ unsigned int cvtpk_bf16(float a, float b) {
    unsigned int r;
    asm("v_cvt_pk_bf16_f32 %0, %1, %2" : "=v"(r) : "v"(a), "v"(b));
    return r;
}

// ---------------------------------------------------------------------------
// MERGED prep kernel:
//   blocks [0, 12288): fp32->bf16 convert of q/k/v (3 x 4096 blocks)
//   blocks [12288, 13312): convert+transpose of Wq/Wk/Wv/Wo (4 x 256 blocks)
// ---------------------------------------------------------------------------
__global__ __launch_bounds__(256) void prep(
    const float* __restrict__ q, const float* __restrict__ k,
    const float* __restrict__ v, unsigned short* __restrict__ qo,
    unsigned short* __restrict__ ko, unsigned short* __restrict__ vo,
    const float* __restrict__ W0, const float* __restrict__ W1,
    const float* __restrict__ W2, const float* __restrict__ W3,
    unsigned short* __restrict__ T0, unsigned short* __restrict__ T1,
    unsigned short* __restrict__ T2, unsigned short* __restrict__ T3)
{
    __shared__ short Ls[64 * 65];
    const int bid = blockIdx.x;
    const int t = threadIdx.x;
    if (bid < 12288) {
        const int z = bid >> 12, blk = bid & 4095;
        const float* in = (z == 0) ? q : (z == 1) ? k : v;
        unsigned short* out = (z == 0) ? qo : (z == 1) ? ko : vo;
        const int i = (blk * 256 + t) * 4;
        const float4 x = *(const float4*)(in + i);
        ushort4 o; o.x = f2b(x.x); o.y = f2b(x.y); o.z = f2b(x.z); o.w = f2b(x.w);
        *(ushort4*)(out + i) = o;
        return;
    }
    const int r = bid - 12288;                   // [0,1024)
    const int z = r >> 8, rem = r & 255;
    const int k0 = (rem >> 4) * 64, n0 = (rem & 15) * 64;
    const float* W = (z == 0) ? W0 : (z == 1) ? W1 : (z == 2) ? W2 : W3;
    unsigned short* T = (z == 0) ? T0 : (z == 1) ? T1 : (z == 2) ? T2 : T3;
#pragma unroll
    for (int ii = 0; ii < 4; ++ii) {
        const int kl = (t >> 4) + 16 * ii, nl = (t & 15) * 4;
        const float4 vv = *(const float4*)&W[(size_t)(k0 + kl) * 1024 + n0 + nl];
        Ls[kl * 65 + nl + 0] = (short)f2b(vv.x);
        Ls[kl * 65 + nl + 1] = (short)f2b(vv.y);
        Ls[kl * 65 + nl + 2] = (short)f2b(vv.z);
        Ls[kl * 65 + nl + 3] = (short)f2b(vv.w);
    }
    __syncthreads();
#pragma unroll
    for (int ii = 0; ii < 4; ++ii) {
        const int nl = (t >> 4) + 16 * ii, kl = (t & 15) * 4;
        ushort4 o;
        o.x = (unsigned short)Ls[(kl + 0) * 65 + nl];
        o.y = (unsigned short)Ls[(kl + 1) * 65 + nl];
        o.z = (unsigned short)Ls[(kl + 2) * 65 + nl];
        o.w = (unsigned short)Ls[(kl + 3) * 65 + nl];
        *(ushort4*)&T[(size_t)(n0 + nl) * 1024 + k0 + kl] = o;
    }
}

// ---------------------------------------------------------------------------
// MERGED projection GEMM: [4096x1024]bf16 x Bt[3072x1024]^T. BK=64 with
// XOR-swizzled LDS (source col-block (t&7)^((t>>3)&7), linear dest, XOR'd
// read). XCD-panel-chunked: 24 n-tiles per m-panel all on one XCD.
// ---------------------------------------------------------------------------
__global__ __launch_bounds__(256) void gemm_proj(
    const unsigned short* __restrict__ qb, const unsigned short* __restrict__ kb,
    const unsigned short* __restrict__ vb,
    const unsigned short* __restrict__ BtAll,   // merged [3072][1024]
    unsigned short* __restrict__ Qw, unsigned short* __restrict__ Kw,
    unsigned short* __restrict__ Vw,
    const float* __restrict__ iq, const float* __restrict__ ik,
    const float* __restrict__ iv)
{
    const unsigned hw = blockIdx.x;
    const unsigned xcd = hw & 7, j = hw >> 3;       // j in [0,96)
    const unsigned mloc = j / 24, ntg = j - mloc * 24;
    const int mt = (int)(xcd * 4 + mloc);
    const int z = (int)(ntg >> 3), ntl = (int)(ntg & 7);
    const int m0 = mt * 128, n0 = (int)ntg * 128;

    const unsigned short* A = (z == 0) ? qb : (z == 1) ? kb : vb;
    unsigned short* Cw      = (z == 0) ? Qw : (z == 1) ? Kw : Vw;
    const float* msk        = (z == 0) ? iq : (z == 1) ? ik : iv;
    const float scale = (z == 0) ? 0.125f * 1.44269504088896f : 1.0f;

    __shared__ __align__(16) short As[128 * 64];
    __shared__ __align__(16) short Bs[128 * 64];
    __shared__ float maskL[128];
    const int t = threadIdx.x;
    const int w = t >> 6, lane = t & 63, l15 = lane & 15, quad = lane >> 4;
    const int wr = w >> 1, wc = w & 1;
    if (t < 128) maskL[t] = msk[m0 + t] * scale;

    const int srow = t >> 3;
    const int scol = ((t & 7) ^ ((t >> 3) & 7)) * 8;   // constant per thread
    const int l7 = l15 & 7;

    f32x4 zero4 = {0.f, 0.f, 0.f, 0.f};
    f32x4 acc[4][4];
#pragma unroll
    for (int i = 0; i < 4; ++i)
#pragma unroll
        for (int j2 = 0; j2 < 4; ++j2) acc[i][j2] = zero4;

    for (int k0 = 0; k0 < 1024; k0 += 64) {
        __syncthreads();
#pragma unroll
        for (int u = 0; u < 4; ++u) {
            const int r = u * 32 + srow;
            async_ld16(As + u * 2048 + t * 8, A     + (size_t)(m0 + r) * 1024 + k0 + scol);
            async_ld16(Bs + u * 2048 + t * 8, BtAll + (size_t)(n0 + r) * 1024 + k0 + scol);
        }
        __syncthreads();
#pragma unroll
        for (int ks = 0; ks < 2; ++ks) {
            const int cb = ((4 * ks + quad) ^ l7) * 8;  // swizzled read colblk
            bf16x8 af[4], bfr[4];
#pragma unroll
            for (int i = 0; i < 4; ++i)
                af[i] = *(const bf16x8*)&As[(64 * wr + 16 * i + l15) * 64 + cb];
#pragma unroll
            for (int j2 = 0; j2 < 4; ++j2)
                bfr[j2] = *(const bf16x8*)&Bs[(64 * wc + 16 * j2 + l15) * 64 + cb];
            __builtin_amdgcn_s_setprio(1);
#pragma unroll
            for (int i = 0; i < 4; ++i)
#pragma unroll
                for (int j2 = 0; j2 < 4; ++j2)
                    acc[i][j2] = mfma16(af[i], bfr[j2], acc[i][j2]);
            __builtin_amdgcn_s_setprio(0);
        }
    }

    const int h = 2 * ntl + wc;  // 64-col wave tile == one head
#pragma unroll
    for (int i = 0; i < 4; ++i)
#pragma unroll
        for (int j2 = 0; j2 < 4; ++j2)
#pragma unroll
            for (int reg = 0; reg < 4; ++reg) {
                const int mloc2 = 64 * wr + 16 * i + 4 * quad + reg;
                const int m = m0 + mloc2;
                const int bb = m >> 11, s = m & 2047;
                const int hd = 16 * j2 + l15;
                Cw[((size_t)(bb * 16 + h) * 2048 + s) * 64 + hd] =
                    f2b(acc[i][j2][reg] * maskL[mloc2]);
            }
}

// ---------------------------------------------------------------------------
// Output GEMM: out[4096x1024]f32 = AO bf16 @ Wot^T. BM=128 BN=64, BK=64,
// XOR-swizzle, XCD-panel-chunked grid 512.
// ---------------------------------------------------------------------------
__global__ __launch_bounds__(256) void gemm_out(
    const unsigned short* __restrict__ A, const unsigned short* __restrict__ Bt,
    float* __restrict__ C)
{
    __shared__ __align__(16) short As[128 * 64];
    __shared__ __align__(16) short Bs[64 * 64];
    const int t = threadIdx.x;
    const int w = t >> 6, lane = t & 63, l15 = lane & 15, quad = lane >> 4;
    const int wr = w >> 1, wc = w & 1;
    const unsigned hw = blockIdx.x;
    const unsigned xcd = hw & 7, j = hw >> 3;
    const unsigned mt = xcd * 4 + (j >> 4);
    const unsigned nt = j & 15;
    const int n0 = nt * 64, m0 = mt * 128;

    const int srow = t >> 3;
    const int scol = ((t & 7) ^ ((t >> 3) & 7)) * 8;   // constant per thread
    const int l7 = l15 & 7;

    f32x4 zero4 = {0.f, 0.f, 0.f, 0.f};
    f32x4 acc[4][2];
#pragma unroll
    for (int i = 0; i < 4; ++i) { acc[i][0] = zero4; acc[i][1] = zero4; }

    for (int k0 = 0; k0 < 1024; k0 += 64) {
        __syncthreads();
#pragma unroll
        for (int u = 0; u < 4; ++u)
            async_ld16(As + u * 2048 + t * 8, A + (size_t)(m0 + u * 32 + srow) * 1024 + k0 + scol);
#pragma unroll
        for (int u = 0; u < 2; ++u)
            async_ld16(Bs + u * 2048 + t * 8, Bt + (size_t)(n0 + u * 32 + srow) * 1024 + k0 + scol);
        __syncthreads();
#pragma unroll
        for (int ks = 0; ks < 2; ++ks) {
            const int cb = ((4 * ks + quad) ^ l7) * 8;
            bf16x8 af[4], bfr[2];
#pragma unroll
            for (int i = 0; i < 4; ++i)
                af[i] = *(const bf16x8*)&As[(64 * wr + 16 * i + l15) * 64 + cb];
#pragma unroll
            for (int jj = 0; jj < 2; ++jj)
                bfr[jj] = *(const bf16x8*)&Bs[(32 * wc + 16 * jj + l15) * 64 + cb];
            __builtin_amdgcn_s_setprio(1);
#pragma unroll
            for (int i = 0; i < 4; ++i)
#pragma unroll
                for (int jj = 0; jj < 2; ++jj)
                    acc[i][jj] = mfma16(af[i], bfr[jj], acc[i][jj]);
            __builtin_amdgcn_s_setprio(0);
        }
    }
#pragma unroll
    for (int i = 0; i < 4; ++i)
#pragma unroll
        for (int jj = 0; jj < 2; ++jj)
#pragma unroll
            for (int reg = 0; reg < 4; ++reg) {
                const int m = m0 + 64 * wr + 16 * i + 4 * quad + reg;
                const int n = n0 + 32 * wc + 16 * jj + l15;
                C[(size_t)m * 1024 + n] = acc[i][jj][reg];
            }
}

#define GST 72  // attn LDS row stride (shorts): 144B, b128-aligned

// ---------------------------------------------------------------------------
// MFMA flash attention v5 (verified session best: attn 54.5-55.3 us):
//  - 128q/8-wave blocks, XCD-chunked grid, key-permuted QK (P in registers),
//    no-max exp2 softmax, LDS bias table, reg-staged K with row-permute,
//    l via ones-B MFMA on the matrix pipe.
//  - Bracketing results: 64-key chunks optimal (32-key @64q and 128-key both
//    regress); gload_lds-direct K regresses; conflict-halving no effect.
// ---------------------------------------------------------------------------
__global__ __launch_bounds__(512, 4) void attn_mfma(
    const unsigned short* __restrict__ Qw, const unsigned short* __restrict__ Kw,
    const unsigned short* __restrict__ Vw, const float* __restrict__ indk,
    unsigned short* __restrict__ AO)
{
    __shared__ __align__(16) short Ks[2][64 * GST];
    __shared__ __align__(16) short Vt[2][64 * GST];   // Vt[dim][key]
    __shared__ float Bl[2048];                         // bias per key, whole seq
    const int t = threadIdx.x;
    const int w = t >> 6, lane = t & 63, l15 = lane & 15, quad = lane >> 4;
    const unsigned wg = (blockIdx.x & 7) * 64 + (blockIdx.x >> 3);
    const int q0 = (wg & 15) * 128;
    const int h = (wg >> 4) & 15, b = wg >> 8;
    const size_t base = (size_t)(b * 16 + h) * (2048 * 64);
    const unsigned short* Qb = Qw + base + (size_t)q0 * 64;
    const unsigned short* Kb = Kw + base;
    const unsigned short* Vb = Vw + base;

    bf16x8 qf[2];
    qf[0] = *(const bf16x8*)&Qb[(16 * w + l15) * 64 + 8 * quad];
    qf[1] = *(const bf16x8*)&Qb[(16 * w + l15) * 64 + 32 + 8 * quad];

    {
        const float4 bi = *(const float4*)&indk[b * 2048 + t * 4];
        float4 bo;
        bo.x = (bi.x - 1.f) * 1e30f; bo.y = (bi.y - 1.f) * 1e30f;
        bo.z = (bi.z - 1.f) * 1e30f; bo.w = (bi.w - 1.f) * 1e30f;
        *(float4*)&Bl[t * 4] = bo;
    }

    const int skr = t >> 3, skc = (t & 7) * 8;
    const int slr = skr ^ (((skr >> 3) & 1) << 2);
    const int dq = t >> 5, kp2 = (t & 31) * 2;

    bf16x8 kreg;
    ushort4 vreg[2];
    kreg = *(const bf16x8*)&Kb[(size_t)skr * 64 + skc];
    vreg[0] = *(const ushort4*)&Vb[(size_t)kp2 * 64 + 4 * dq];
    vreg[1] = *(const ushort4*)&Vb[(size_t)(kp2 + 1) * 64 + 4 * dq];

    const int u_ = l15 >> 2, a_ = l15 & 3;
    const int krA = 8 * u_ + 4 * (u_ & 1) + a_;
    const int krB = 8 * u_ + 4 * (1 - (u_ & 1)) + a_;

    union { unsigned int u[4]; bf16x8 b; } ones;
    ones.u[0] = 0x3F803F80u; ones.u[1] = 0x3F803F80u;
    ones.u[2] = 0x3F803F80u; ones.u[3] = 0x3F803F80u;

    f32x4 zero4 = {0.f, 0.f, 0.f, 0.f};
    f32x4 oacc[4];
    oacc[0] = zero4; oacc[1] = zero4; oacc[2] = zero4; oacc[3] = zero4;
    f32x4 lacc = zero4;

    for (int c = 0; c < 32; ++c) {
        const int cur = c & 1;
        *(bf16x8*)&Ks[cur][slr * GST + skc] = kreg;
        {
            const unsigned int* v0d = (const unsigned int*)&vreg[0];
            const unsigned int* v1d = (const unsigned int*)&vreg[1];
            *(unsigned int*)&Vt[cur][(4 * dq + 0) * GST + kp2] =
                __builtin_amdgcn_perm(v1d[0], v0d[0], 0x05040100u);
            *(unsigned int*)&Vt[cur][(4 * dq + 1) * GST + kp2] =
                __builtin_amdgcn_perm(v1d[0], v0d[0], 0x07060302u);
            *(unsigned int*)&Vt[cur][(4 * dq + 2) * GST + kp2] =
                __builtin_amdgcn_perm(v1d[1], v0d[1], 0x05040100u);
            *(unsigned int*)&Vt[cur][(4 * dq + 3) * GST + kp2] =
                __builtin_amdgcn_perm(v1d[1], v0d[1], 0x07060302u);
        }
        __syncthreads();  // the ONLY barrier per chunk
        {
            const int kn = (c < 31 ? c + 1 : 31) * 64;
            kreg = *(const bf16x8*)&Kb[(size_t)(kn + skr) * 64 + skc];
            vreg[0] = *(const ushort4*)&Vb[(size_t)(kn + kp2) * 64 + 4 * dq];
            vreg[1] = *(const ushort4*)&Vb[(size_t)(kn + kp2 + 1) * 64 + 4 * dq];
        }
        const short* KsC = Ks[cur];
        const short* VtC = Vt[cur];
        const float* BlC = Bl + c * 64;

        f32x4 sacc[4];
#pragma unroll
        for (int g = 0; g < 4; ++g) {
            const float4 bv = *(const float4*)&BlC[32 * (g >> 1) + 4 * (g & 1) + 8 * quad];
            sacc[g][0] = bv.x; sacc[g][1] = bv.y; sacc[g][2] = bv.z; sacc[g][3] = bv.w;
        }
        __builtin_amdgcn_s_setprio(1);
#pragma unroll
        for (int ks = 0; ks < 2; ++ks)
#pragma unroll
            for (int g = 0; g < 4; ++g) {
                const int row = 32 * (g >> 1) + ((g & 1) ? krB : krA);
                const bf16x8 kf = *(const bf16x8*)&KsC[row * GST + 32 * ks + 8 * quad];
                sacc[g] = mfma16(kf, qf[ks], sacc[g]);
            }
        __builtin_amdgcn_s_setprio(0);

        unsigned int dw[4][2];
#pragma unroll
        for (int g = 0; g < 4; ++g) {
#pragma unroll
            for (int r = 0; r < 4; ++r) sacc[g][r] = exp2_hw(sacc[g][r]);
            dw[g][0] = cvtpk_bf16(sacc[g][0], sacc[g][1]);
            dw[g][1] = cvtpk_bf16(sacc[g][2], sacc[g][3]);
        }

        __builtin_amdgcn_s_setprio(1);
#pragma unroll
        for (int ks = 0; ks < 2; ++ks) {
            union { unsigned int u[4]; bf16x8 b; } pc;
            pc.u[0] = dw[2 * ks][0];     pc.u[1] = dw[2 * ks][1];
            pc.u[2] = dw[2 * ks + 1][0]; pc.u[3] = dw[2 * ks + 1][1];
#pragma unroll
            for (int nj = 0; nj < 4; ++nj) {
                const bf16x8 vbf = *(const bf16x8*)
                    &VtC[(16 * nj + l15) * GST + 32 * ks + 8 * quad];
                oacc[nj] = mfma16(pc.b, vbf, oacc[nj]);
            }
            lacc = mfma16(pc.b, ones.b, lacc);
        }
        __builtin_amdgcn_s_setprio(0);
    }

    float invr[4];
#pragma unroll
    for (int r = 0; r < 4; ++r)
        invr[r] = (lacc[r] > 0.f) ? 1.f / lacc[r] : 0.f;  // zero-row guard
#pragma unroll
    for (int nj = 0; nj < 4; ++nj)
#pragma unroll
        for (int r = 0; r < 4; ++r) {
            const int row = q0 + 16 * w + 4 * quad + r;
            AO[(size_t)(b * 2048 + row) * 1024 + h * 64 + 16 * nj + l15] =
                f2b(oacc[nj][r] * invr[r]);
        }
}

// ---------------------------------------------------------------------------
extern "C" void kernel_launch(void* const* d_in, const int* in_sizes, int n_in,
                              void* d_out, int out_size, void* d_ws, size_t ws_size,
                              hipStream_t stream) {
    const float* q  = (const float*)d_in[0];
    const float* k  = (const float*)d_in[1];
    const float* v  = (const float*)d_in[2];
    const float* iq = (const float*)d_in[3];
    const float* ik = (const float*)d_in[4];
    const float* iv = (const float*)d_in[5];
    const float* Wq = (const float*)d_in[6];
    const float* Wk = (const float*)d_in[7];
    const float* Wv = (const float*)d_in[8];
    const float* Wo = (const float*)d_in[9];
    float* out = (float*)d_out;
    unsigned short* ws = (unsigned short*)d_ws;

    const size_t M1 = 1048576;
    unsigned short* qb  = ws;
    unsigned short* kb  = ws + 4  * M1;
    unsigned short* vb  = ws + 8  * M1;
    unsigned short* Wqt = ws + 12 * M1;  // Wqt|Wkt|Wvt contiguous = merged Bt
    unsigned short* Wkt = ws + 13 * M1;
    unsigned short* Wvt = ws + 14 * M1;
    unsigned short* Wot = ws + 15 * M1;
    unsigned short* Qw  = ws + 16 * M1;
    unsigned short* Kw  = ws + 20 * M1;
    unsigned short* Vw  = ws + 24 * M1;
    unsigned short* AO  = ws + 28 * M1;

    prep<<<dim3(13312, 1, 1), dim3(256), 0, stream>>>(
        q, k, v, qb, kb, vb, Wq, Wk, Wv, Wo, Wqt, Wkt, Wvt, Wot);
    gemm_proj<<<dim3(768, 1, 1), dim3(256), 0, stream>>>(
        qb, kb, vb, Wqt, Qw, Kw, Vw, iq, ik, iv);
    attn_mfma<<<dim3(512, 1, 1), dim3(512), 0, stream>>>(Qw, Kw, Vw, ik, AO);
    gemm_out<<<dim3(512, 1, 1), dim3(256), 0, stream>>>(AO, Wot, out);
}